// Round 1
// baseline (31872.559 us; speedup 1.0000x reference)
//
#include <hip/hip_runtime.h>
#include <math.h>

namespace {
constexpr int B    = 1024;
constexpr int T    = 168;
constexpr int D    = 32;
constexpr int H    = 512;
constexpr int KOUT = 8;
constexpr int TAU  = 24;

constexpr int BT = 32;   // batch rows per block
constexpr int JT = 64;   // hidden units per block
constexpr int KC = 32;   // K chunk depth
}

__device__ __forceinline__ float sig_(float x) { return 1.0f / (1.0f + expf(-x)); }

extern "C" __global__ void __launch_bounds__(256)
zero_f32(float* p, int n)
{
    int i = blockIdx.x * 256 + threadIdx.x;
    if (i < n) p[i] = 0.0f;
}

// gates = Xin @ Wih^T + Hold @ Whh^T + bih + bhh ; LSTM pointwise ; write c,h
// Block computes a [BT x JT] tile of hidden units for all 4 gates.
extern "C" __global__ void __launch_bounds__(256)
lstm_cell(const float* __restrict__ Xin, int ldx, int Kx,
          const float* __restrict__ Wih,
          const float* __restrict__ Hold,
          const float* __restrict__ Whh,
          const float* __restrict__ bih,
          const float* __restrict__ bhh,
          float* __restrict__ c_state,
          float* __restrict__ h_out)
{
    __shared__ float A_s[KC][BT + 4];     // [kk][row], pad keeps b128 reads conflict-free
    __shared__ float W_s[4][KC][JT];      // [gate][kk][j], j XOR-swizzled by (kk&62)

    const int tid  = threadIdx.x;
    const int tx   = tid & 31;            // 2 cols each
    const int ty   = tid >> 5;            // 4 rows each
    const int row0 = blockIdx.x * BT;
    const int j0   = blockIdx.y * JT;

    const int r_st = tid >> 3;            // 0..31: A row / W row-in-pass
    const int kq   = (tid & 7) << 2;      // float4 k offset within chunk

    float acc[4][4][2];
    #pragma unroll
    for (int g = 0; g < 4; ++g)
        #pragma unroll
        for (int i = 0; i < 4; ++i) { acc[g][i][0] = 0.f; acc[g][i][1] = 0.f; }

    const int nx     = Kx / KC;           // chunks in input phase
    const int nchunk = nx + H / KC;

    float4 areg;
    float4 wreg[8];

    auto load_chunk = [&](int ci) {
        const float* Ap; const float* Wp; int lda, Kw, k0;
        if (ci < nx) { Ap = Xin;  Wp = Wih; lda = ldx; Kw = Kx; k0 = ci * KC; }
        else         { Ap = Hold; Wp = Whh; lda = H;   Kw = H;  k0 = (ci - nx) * KC; }
        areg = *(const float4*)&Ap[(size_t)(row0 + r_st) * lda + k0 + kq];
        #pragma unroll
        for (int pp = 0; pp < 8; ++pp) {
            int rr = pp * 32 + r_st;                 // 0..255 = gate*64 + j
            int g = rr >> 6, j = rr & 63;
            wreg[pp] = *(const float4*)&Wp[(size_t)(g * H + j0 + j) * Kw + k0 + kq];
        }
    };

    auto store_chunk = [&]() {
        A_s[kq + 0][r_st] = areg.x;
        A_s[kq + 1][r_st] = areg.y;
        A_s[kq + 2][r_st] = areg.z;
        A_s[kq + 3][r_st] = areg.w;
        const float* wv;
        #pragma unroll
        for (int pp = 0; pp < 8; ++pp) {
            int rr = pp * 32 + r_st;
            int g = rr >> 6, j = rr & 63;
            wv = (const float*)&wreg[pp];
            #pragma unroll
            for (int q = 0; q < 4; ++q) {
                int kk = kq + q;
                W_s[g][kk][j ^ (kk & 62)] = wv[q];   // swizzle: 8-way -> 2-way (free)
            }
        }
    };

    load_chunk(0);
    for (int ci = 0; ci < nchunk; ++ci) {
        __syncthreads();
        store_chunk();
        __syncthreads();
        if (ci + 1 < nchunk) load_chunk(ci + 1);     // prefetch hides under FMAs
        #pragma unroll
        for (int kk = 0; kk < KC; ++kk) {
            float4 a = *(const float4*)&A_s[kk][ty * 4];
            const float* av = (const float*)&a;
            #pragma unroll
            for (int g = 0; g < 4; ++g) {
                float2 w = *(const float2*)&W_s[g][kk][(tx * 2) ^ (kk & 62)];
                #pragma unroll
                for (int i = 0; i < 4; ++i) {
                    acc[g][i][0] = fmaf(av[i], w.x, acc[g][i][0]);
                    acc[g][i][1] = fmaf(av[i], w.y, acc[g][i][1]);
                }
            }
        }
    }

    // epilogue: biases + LSTM cell update
    const int j = j0 + tx * 2;
    float bi0 = bih[0 * H + j]     + bhh[0 * H + j];
    float bi1 = bih[0 * H + j + 1] + bhh[0 * H + j + 1];
    float bf0 = bih[1 * H + j]     + bhh[1 * H + j];
    float bf1 = bih[1 * H + j + 1] + bhh[1 * H + j + 1];
    float bg0 = bih[2 * H + j]     + bhh[2 * H + j];
    float bg1 = bih[2 * H + j + 1] + bhh[2 * H + j + 1];
    float bo0 = bih[3 * H + j]     + bhh[3 * H + j];
    float bo1 = bih[3 * H + j + 1] + bhh[3 * H + j + 1];

    #pragma unroll
    for (int i = 0; i < 4; ++i) {
        int b = row0 + ty * 4 + i;
        size_t base = (size_t)b * H + j;
        float2 cold = *(const float2*)&c_state[base];
        float pi0 = acc[0][i][0] + bi0, pi1 = acc[0][i][1] + bi1;
        float pf0 = acc[1][i][0] + bf0, pf1 = acc[1][i][1] + bf1;
        float pg0 = acc[2][i][0] + bg0, pg1 = acc[2][i][1] + bg1;
        float po0 = acc[3][i][0] + bo0, po1 = acc[3][i][1] + bo1;
        float2 cn, hn;
        cn.x = sig_(pf0) * cold.x + sig_(pi0) * tanhf(pg0);
        cn.y = sig_(pf1) * cold.y + sig_(pi1) * tanhf(pg1);
        hn.x = sig_(po0) * tanhf(cn.x);
        hn.y = sig_(po1) * tanhf(cn.y);
        *(float2*)&c_state[base] = cn;
        *(float2*)&h_out[base]   = hn;
    }
}

// mu = h@W1^T + b1 ; sigma = softplus(2*(h@W2^T+b2))/2  for one decoder step t
extern "C" __global__ void __launch_bounds__(256)
head_kernel(const float* __restrict__ htop,
            const float* __restrict__ W1, const float* __restrict__ b1,
            const float* __restrict__ W2, const float* __restrict__ b2,
            float* __restrict__ out, int t)
{
    int idx = blockIdx.x * 256 + threadIdx.x;   // 0..16383
    int b = idx >> 4;
    int r = idx & 15;
    int k = r & 7;
    int which = r >> 3;
    const float* w = (which ? W2 : W1) + (size_t)k * H;
    const float* h = htop + (size_t)b * H;
    float sum = 0.f;
    #pragma unroll 4
    for (int d = 0; d < H; d += 4) {
        float4 hv = *(const float4*)&h[d];
        float4 wv = *(const float4*)&w[d];
        sum = fmaf(hv.x, wv.x, sum);
        sum = fmaf(hv.y, wv.y, sum);
        sum = fmaf(hv.z, wv.z, sum);
        sum = fmaf(hv.w, wv.w, sum);
    }
    size_t o = ((size_t)b * TAU + t) * KOUT + k;
    if (which == 0) {
        out[o] = sum + b1[k];
    } else {
        float z  = 2.0f * (sum + b2[k]);
        float sp = fmaxf(z, 0.0f) + log1pf(expf(-fabsf(z)));   // stable softplus
        out[(size_t)B * TAU * KOUT + o] = 0.5f * sp;
    }
}

extern "C" void kernel_launch(void* const* d_in, const int* in_sizes, int n_in,
                              void* d_out, int out_size, void* d_ws, size_t ws_size,
                              hipStream_t stream)
{
    (void)in_sizes; (void)n_in; (void)out_size; (void)ws_size;

    const float* x     = (const float*)d_in[0];
    const float* eWih0 = (const float*)d_in[1];
    const float* eWhh0 = (const float*)d_in[2];
    const float* ebih0 = (const float*)d_in[3];
    const float* ebhh0 = (const float*)d_in[4];
    const float* eWih1 = (const float*)d_in[5];
    const float* eWhh1 = (const float*)d_in[6];
    const float* ebih1 = (const float*)d_in[7];
    const float* ebhh1 = (const float*)d_in[8];
    const float* dWih0 = (const float*)d_in[9];
    const float* dWhh0 = (const float*)d_in[10];
    const float* dbih0 = (const float*)d_in[11];
    const float* dbhh0 = (const float*)d_in[12];
    const float* dWih1 = (const float*)d_in[13];
    const float* dWhh1 = (const float*)d_in[14];
    const float* dbih1 = (const float*)d_in[15];
    const float* dbhh1 = (const float*)d_in[16];
    const float* W1    = (const float*)d_in[17];
    const float* b1    = (const float*)d_in[18];
    const float* W2    = (const float*)d_in[19];
    const float* b2    = (const float*)d_in[20];
    float* out = (float*)d_out;

    float* ws = (float*)d_ws;
    const size_t NH = (size_t)B * H;          // 524288 floats
    float* h0[2] = { ws,          ws + NH };
    float* h1[2] = { ws + 2 * NH, ws + 3 * NH };
    float* c0 = ws + 4 * NH;
    float* c1 = ws + 5 * NH;

    // zero all state each call (harness does not re-poison between replays)
    {
        int n = (int)(6 * NH);
        zero_f32<<<dim3((n + 255) / 256), dim3(256), 0, stream>>>(ws, n);
    }

    const dim3 grid(B / BT, H / JT);   // 32 x 8 = 256 blocks
    const dim3 blk(256);

    int p = 0;
    for (int t = 0; t < T; ++t) {
        lstm_cell<<<grid, blk, 0, stream>>>(x + (size_t)t * D, T * D, D,
            eWih0, h0[p], eWhh0, ebih0, ebhh0, c0, h0[p ^ 1]);
        lstm_cell<<<grid, blk, 0, stream>>>(h0[p ^ 1], H, H,
            eWih1, h1[p], eWhh1, ebih1, ebhh1, c1, h1[p ^ 1]);
        p ^= 1;
    }
    for (int t = 0; t < TAU; ++t) {
        lstm_cell<<<grid, blk, 0, stream>>>(h1[p], H, H,
            dWih0, h0[p], dWhh0, dbih0, dbhh0, c0, h0[p ^ 1]);
        lstm_cell<<<grid, blk, 0, stream>>>(h0[p ^ 1], H, H,
            dWih1, h1[p], dWhh1, dbih1, dbhh1, c1, h1[p ^ 1]);
        head_kernel<<<dim3(64), blk, 0, stream>>>(h1[p ^ 1], W1, b1, W2, b2, out, t);
        p ^= 1;
    }
}

// Round 2
// 15155.000 us; speedup vs baseline: 2.1031x; 2.1031x over previous
//
#include <hip/hip_runtime.h>
#include <math.h>

typedef unsigned short u16;
typedef unsigned int   u32;
typedef __attribute__((ext_vector_type(8))) short bf16x8;
typedef __attribute__((ext_vector_type(4))) float f32x4;

namespace {
constexpr int B_ = 1024, T_ = 168, D_ = 32, H_ = 512, K_ = 8, TAU_ = 24;
}

__device__ __forceinline__ u16 f2bf(float x) {
    u32 u = __float_as_uint(x);
    return (u16)((u + 0x7fffu + ((u >> 16) & 1u)) >> 16);
}
__device__ __forceinline__ float bf2f(u16 b) { return __uint_as_float(((u32)b) << 16); }
__device__ __forceinline__ float sig_(float x) { return 1.0f / (1.0f + expf(-x)); }

__device__ __forceinline__ void gl16(const void* g, void* l) {
    __builtin_amdgcn_global_load_lds((const __attribute__((address_space(1))) void*)g,
                                     (__attribute__((address_space(3))) void*)l, 16, 0, 0);
}

struct CellA {
    const u16 *Ah, *Al; long lda; long Kx;      // input activations (hi/lo bf16)
    const u16 *Wih_h, *Wih_l;                   // [2048, Kx]
    const u16 *Hh, *Hl;                         // recurrent h (hi/lo), [B,512]
    const u16 *Whh_h, *Whh_l;                   // [2048, 512]
    const float *bih, *bhh;
    float *c;                                   // cell state fp32 [B,512]
    u16 *oh, *ol;                               // h output hi/lo
};

// gates = A@Wih^T + H@Whh^T (double-bf16 split, fp32 MFMA accum) ; LSTM epilogue.
// Block: 64 rows x 16 j (all 4 gates). 4 waves stacked in M. Wave tile 16x64.
extern "C" __global__ void __launch_bounds__(256, 4)
cell_kernel(CellA a0, CellA a1)
{
    __shared__ u16 As[8 * 64 * 8];   // [kchunk c:8][row:64][8 bf16]
    __shared__ u16 Ws[8 * 64 * 8];   // [c:8][wrow:64][8],  wrow = gate*16 + jj

    const CellA& A = (blockIdx.z == 0) ? a0 : a1;

    const int tid  = threadIdx.x;
    const int wid  = tid >> 6;
    const int lane = tid & 63;
    const int l16  = lane & 15, lq = lane >> 4;
    const int row0 = blockIdx.x * 64;
    const int j0   = blockIdx.y * 16;

    const int  sc   = tid >> 6;          // staging k-subchunk (8 bf16)
    const int  srow = tid & 63;          // A row / W wrow within tile
    const long wgrow = (long)(srow >> 4) * H_ + j0 + (srow & 15);  // W global row

    f32x4 acc[4];
    #pragma unroll
    for (int g = 0; g < 4; ++g)
        #pragma unroll
        for (int q = 0; q < 4; ++q) acc[g][q] = 0.f;

    u16* dstA0 = &As[tid * 8];          u16* dstA1 = &As[(tid + 256) * 8];
    u16* dstW0 = &Ws[tid * 8];          u16* dstW1 = &Ws[(tid + 256) * 8];

    const int aoff0 = lq * 512 + (wid * 16 + l16) * 8;
    const int aoff1 = aoff0 + 4 * 512;

    #pragma unroll
    for (int s = 0; s < 6; ++s) {
        const u16* Ap; const u16* Wp; long lda; long K;
        if      (s == 0) { Ap = A.Ah; Wp = A.Wih_h; lda = A.lda; K = A.Kx; }
        else if (s == 1) { Ap = A.Ah; Wp = A.Wih_l; lda = A.lda; K = A.Kx; }
        else if (s == 2) { Ap = A.Al; Wp = A.Wih_h; lda = A.lda; K = A.Kx; }
        else if (s == 3) { Ap = A.Hh; Wp = A.Whh_h; lda = H_;   K = H_;   }
        else if (s == 4) { Ap = A.Hh; Wp = A.Whh_l; lda = H_;   K = H_;   }
        else             { Ap = A.Hl; Wp = A.Whh_h; lda = H_;   K = H_;   }

        const u16* Ab = Ap + (long)(row0 + srow) * lda + sc * 8;
        const u16* Wb = Wp + wgrow * K + sc * 8;

        for (long k0 = 0; k0 < K; k0 += 64) {
            const bool full = (K - k0) >= 64;
            __syncthreads();                       // prev compute done
            gl16(Ab + k0, dstA0);
            gl16(Wb + k0, dstW0);
            if (full) { gl16(Ab + k0 + 32, dstA1); gl16(Wb + k0 + 32, dstW1); }
            __syncthreads();                       // implicit vmcnt(0): staged data visible

            bf16x8 av = *(const bf16x8*)&As[aoff0];
            #pragma unroll
            for (int g = 0; g < 4; ++g) {
                bf16x8 wv = *(const bf16x8*)&Ws[lq * 512 + (g * 16 + l16) * 8];
                acc[g] = __builtin_amdgcn_mfma_f32_16x16x32_bf16(av, wv, acc[g], 0, 0, 0);
            }
            if (full) {
                bf16x8 av1 = *(const bf16x8*)&As[aoff1];
                #pragma unroll
                for (int g = 0; g < 4; ++g) {
                    bf16x8 wv = *(const bf16x8*)&Ws[(4 + lq) * 512 + (g * 16 + l16) * 8];
                    acc[g] = __builtin_amdgcn_mfma_f32_16x16x32_bf16(av1, wv, acc[g], 0, 0, 0);
                }
            }
        }
    }

    // epilogue: C/D layout col=lane&15, row=(lane>>4)*4+reg  -> all 4 gates in-lane
    const int jj = j0 + l16;
    const float bi = A.bih[jj]          + A.bhh[jj];
    const float bf = A.bih[H_ + jj]     + A.bhh[H_ + jj];
    const float bg = A.bih[2 * H_ + jj] + A.bhh[2 * H_ + jj];
    const float bo = A.bih[3 * H_ + jj] + A.bhh[3 * H_ + jj];
    #pragma unroll
    for (int r = 0; r < 4; ++r) {
        const int  b    = row0 + wid * 16 + lq * 4 + r;
        const long base = (long)b * H_ + jj;
        const float cold = A.c[base];
        const float pi = acc[0][r] + bi, pf = acc[1][r] + bf;
        const float pg = acc[2][r] + bg, po = acc[3][r] + bo;
        const float cn = sig_(pf) * cold + sig_(pi) * tanhf(pg);
        const float hn = sig_(po) * tanhf(cn);
        A.c[base] = cn;
        const u16 hh = f2bf(hn);
        A.oh[base] = hh;
        A.ol[base] = f2bf(hn - bf2f(hh));
    }
}

// fp32 -> bf16 hi/lo split, 4 elements per thread
extern "C" __global__ void __launch_bounds__(256)
split4(const float* __restrict__ in, u16* __restrict__ hi, u16* __restrict__ lo, int n4)
{
    int i = blockIdx.x * 256 + threadIdx.x;
    if (i < n4) {
        float4 v = ((const float4*)in)[i];
        u16 h0 = f2bf(v.x), h1 = f2bf(v.y), h2 = f2bf(v.z), h3 = f2bf(v.w);
        ushort4 Hv; Hv.x = h0; Hv.y = h1; Hv.z = h2; Hv.w = h3;
        ushort4 Lv;
        Lv.x = f2bf(v.x - bf2f(h0)); Lv.y = f2bf(v.y - bf2f(h1));
        Lv.z = f2bf(v.z - bf2f(h2)); Lv.w = f2bf(v.w - bf2f(h3));
        ((ushort4*)hi)[i] = Hv; ((ushort4*)lo)[i] = Lv;
    }
}

extern "C" __global__ void __launch_bounds__(256)
zero16(uint4* p, int n)
{
    for (int i = blockIdx.x * 256 + threadIdx.x; i < n; i += gridDim.x * 256)
        p[i] = make_uint4(0, 0, 0, 0);
}

// mu / sigma heads for decoder step t ; h reconstructed as hi+lo
extern "C" __global__ void __launch_bounds__(256)
head_kernel(const u16* __restrict__ hh, const u16* __restrict__ hl,
            const float* __restrict__ W1, const float* __restrict__ b1,
            const float* __restrict__ W2, const float* __restrict__ b2,
            float* __restrict__ out, int t)
{
    int idx = blockIdx.x * 256 + threadIdx.x;          // 0..16383
    int b = idx >> 4, r = idx & 15, k = r & 7, which = r >> 3;
    const float* w  = (which ? W2 : W1) + (long)k * H_;
    const u16*   ph = hh + (long)b * H_;
    const u16*   pl = hl + (long)b * H_;
    float sum = 0.f;
    for (int d = 0; d < H_; d += 8) {
        uint4 uh = *(const uint4*)&ph[d];
        uint4 ul = *(const uint4*)&pl[d];
        float4 w0 = *(const float4*)&w[d];
        float4 w1 = *(const float4*)&w[d + 4];
        sum = fmaf(bf2f((u16)(uh.x & 0xffff)) + bf2f((u16)(ul.x & 0xffff)), w0.x, sum);
        sum = fmaf(bf2f((u16)(uh.x >> 16))    + bf2f((u16)(ul.x >> 16)),    w0.y, sum);
        sum = fmaf(bf2f((u16)(uh.y & 0xffff)) + bf2f((u16)(ul.y & 0xffff)), w0.z, sum);
        sum = fmaf(bf2f((u16)(uh.y >> 16))    + bf2f((u16)(ul.y >> 16)),    w0.w, sum);
        sum = fmaf(bf2f((u16)(uh.z & 0xffff)) + bf2f((u16)(ul.z & 0xffff)), w1.x, sum);
        sum = fmaf(bf2f((u16)(uh.z >> 16))    + bf2f((u16)(ul.z >> 16)),    w1.y, sum);
        sum = fmaf(bf2f((u16)(uh.w & 0xffff)) + bf2f((u16)(ul.w & 0xffff)), w1.z, sum);
        sum = fmaf(bf2f((u16)(uh.w >> 16))    + bf2f((u16)(ul.w >> 16)),    w1.w, sum);
    }
    long o = ((long)b * TAU_ + t) * K_ + k;
    if (which == 0) {
        out[o] = sum + b1[k];
    } else {
        float z  = 2.0f * (sum + b2[k]);
        float sp = fmaxf(z, 0.0f) + log1pf(expf(-fabsf(z)));
        out[(long)B_ * TAU_ * K_ + o] = 0.5f * sp;
    }
}

extern "C" void kernel_launch(void* const* d_in, const int* in_sizes, int n_in,
                              void* d_out, int out_size, void* d_ws, size_t ws_size,
                              hipStream_t stream)
{
    (void)in_sizes; (void)n_in; (void)out_size; (void)ws_size;

    const float* x     = (const float*)d_in[0];
    const float* eWih0 = (const float*)d_in[1];
    const float* eWhh0 = (const float*)d_in[2];
    const float* ebih0 = (const float*)d_in[3];
    const float* ebhh0 = (const float*)d_in[4];
    const float* eWih1 = (const float*)d_in[5];
    const float* eWhh1 = (const float*)d_in[6];
    const float* ebih1 = (const float*)d_in[7];
    const float* ebhh1 = (const float*)d_in[8];
    const float* dWih0 = (const float*)d_in[9];
    const float* dWhh0 = (const float*)d_in[10];
    const float* dbih0 = (const float*)d_in[11];
    const float* dbhh0 = (const float*)d_in[12];
    const float* dWih1 = (const float*)d_in[13];
    const float* dWhh1 = (const float*)d_in[14];
    const float* dbih1 = (const float*)d_in[15];
    const float* dbhh1 = (const float*)d_in[16];
    const float* W1    = (const float*)d_in[17];
    const float* b1    = (const float*)d_in[18];
    const float* W2    = (const float*)d_in[19];
    const float* b2    = (const float*)d_in[20];
    float* out = (float*)d_out;

    char* wsp = (char*)d_ws;
    auto take = [&](size_t n) { void* p = (void*)wsp; wsp += n; return p; };

    const size_t NX = (size_t)B_ * T_ * D_;         // 5,505,024
    u16* xh = (u16*)take(NX * 2);
    u16* xl = (u16*)take(NX * 2);

    const float* wsrc[8] = { eWih0, eWhh0, eWih1, eWhh1, dWih0, dWhh0, dWih1, dWhh1 };
    const size_t wn[8]   = { (size_t)2048 * 32, (size_t)2048 * 512, (size_t)2048 * 512,
                             (size_t)2048 * 512, (size_t)2048 * 512, (size_t)2048 * 512,
                             (size_t)2048 * 512, (size_t)2048 * 512 };
    u16 *wh[8], *wl[8];
    for (int i = 0; i < 8; ++i) { wh[i] = (u16*)take(wn[i] * 2); wl[i] = (u16*)take(wn[i] * 2); }

    const size_t NH = (size_t)B_ * H_;              // 524288
    char* state0 = wsp;
    u16 *h0h[2], *h0l[2], *h1h[2], *h1l[2];
    for (int p = 0; p < 2; ++p) { h0h[p] = (u16*)take(NH * 2); h0l[p] = (u16*)take(NH * 2); }
    for (int p = 0; p < 2; ++p) { h1h[p] = (u16*)take(NH * 2); h1l[p] = (u16*)take(NH * 2); }
    float* c0 = (float*)take(NH * 4);
    float* c1 = (float*)take(NH * 4);
    const size_t stateBytes = (size_t)(wsp - state0);

    const dim3 blk(256);

    // conversions (per call; kernel_launch must be stateless)
    split4<<<dim3((unsigned)((NX / 4 + 255) / 256)), blk, 0, stream>>>(x, xh, xl, (int)(NX / 4));
    for (int i = 0; i < 8; ++i)
        split4<<<dim3((unsigned)((wn[i] / 4 + 255) / 256)), blk, 0, stream>>>(wsrc[i], wh[i], wl[i], (int)(wn[i] / 4));
    zero16<<<dim3(1024), blk, 0, stream>>>((uint4*)state0, (int)(stateBytes / 16));

    auto mkL0e = [&](int t, int pin, int pout) {
        CellA c;
        c.Ah = xh + (size_t)t * D_; c.Al = xl + (size_t)t * D_; c.lda = T_ * D_; c.Kx = D_;
        c.Wih_h = wh[0]; c.Wih_l = wl[0];
        c.Hh = h0h[pin]; c.Hl = h0l[pin];
        c.Whh_h = wh[1]; c.Whh_l = wl[1];
        c.bih = ebih0; c.bhh = ebhh0; c.c = c0;
        c.oh = h0h[pout]; c.ol = h0l[pout];
        return c;
    };
    auto mkL1e = [&](int pa, int pin, int pout) {
        CellA c;
        c.Ah = h0h[pa]; c.Al = h0l[pa]; c.lda = H_; c.Kx = H_;
        c.Wih_h = wh[2]; c.Wih_l = wl[2];
        c.Hh = h1h[pin]; c.Hl = h1l[pin];
        c.Whh_h = wh[3]; c.Whh_l = wl[3];
        c.bih = ebih1; c.bhh = ebhh1; c.c = c1;
        c.oh = h1h[pout]; c.ol = h1l[pout];
        return c;
    };
    auto mkL0d = [&](int pa, int pin, int pout) {
        CellA c;
        c.Ah = h1h[pa]; c.Al = h1l[pa]; c.lda = H_; c.Kx = H_;
        c.Wih_h = wh[4]; c.Wih_l = wl[4];
        c.Hh = h0h[pin]; c.Hl = h0l[pin];
        c.Whh_h = wh[5]; c.Whh_l = wl[5];
        c.bih = dbih0; c.bhh = dbhh0; c.c = c0;
        c.oh = h0h[pout]; c.ol = h0l[pout];
        return c;
    };
    auto mkL1d = [&](int pa, int pin, int pout) {
        CellA c;
        c.Ah = h0h[pa]; c.Al = h0l[pa]; c.lda = H_; c.Kx = H_;
        c.Wih_h = wh[6]; c.Wih_l = wl[6];
        c.Hh = h1h[pin]; c.Hl = h1l[pin];
        c.Whh_h = wh[7]; c.Whh_l = wl[7];
        c.bih = dbih1; c.bhh = dbhh1; c.c = c1;
        c.oh = h1h[pout]; c.ol = h1l[pout];
        return c;
    };

    int p0 = 1, p1 = 1;     // zeros live in buffer 1

    { CellA a = mkL0e(0, p0, p0 ^ 1);
      cell_kernel<<<dim3(16, 32, 1), blk, 0, stream>>>(a, a); p0 ^= 1; }

    for (int t = 0; t < T_ - 1; ++t) {               // stagger: L1(t) || L0(t+1)
        CellA l1 = mkL1e(p0, p1, p1 ^ 1);
        CellA l0 = mkL0e(t + 1, p0, p0 ^ 1);
        cell_kernel<<<dim3(16, 32, 2), blk, 0, stream>>>(l1, l0);
        p0 ^= 1; p1 ^= 1;
    }
    { CellA a = mkL1e(p0, p1, p1 ^ 1);
      cell_kernel<<<dim3(16, 32, 1), blk, 0, stream>>>(a, a); p1 ^= 1; }

    for (int t = 0; t < TAU_; ++t) {
        CellA a = mkL0d(p1, p0, p0 ^ 1);
        cell_kernel<<<dim3(16, 32, 1), blk, 0, stream>>>(a, a); p0 ^= 1;
        CellA b_ = mkL1d(p0, p1, p1 ^ 1);
        cell_kernel<<<dim3(16, 32, 1), blk, 0, stream>>>(b_, b_); p1 ^= 1;
        head_kernel<<<dim3(64), blk, 0, stream>>>(h1h[p1], h1l[p1], W1, b1, W2, b2, out, t);
    }
}

// Round 3
// 6349.704 us; speedup vs baseline: 5.0195x; 2.3867x over previous
//
#include <hip/hip_runtime.h>
#include <math.h>

typedef unsigned short u16;
typedef unsigned int   u32;
typedef __attribute__((ext_vector_type(8))) short bf16x8;
typedef __attribute__((ext_vector_type(4))) float f32x4;

namespace {
constexpr int B_ = 1024, T_ = 168, D_ = 32, H_ = 512, K_ = 8, TAU_ = 24;
}

__device__ __forceinline__ u16 f2bf(float x) {
    u32 u = __float_as_uint(x);
    return (u16)((u + 0x7fffu + ((u >> 16) & 1u)) >> 16);
}
__device__ __forceinline__ float bf2f(u16 b) { return __uint_as_float(((u32)b) << 16); }
__device__ __forceinline__ float sig_(float x) { return 1.0f / (1.0f + expf(-x)); }

__device__ __forceinline__ void gl16(const u16* g, void* l) {
    __builtin_amdgcn_global_load_lds((const __attribute__((address_space(1))) void*)g,
                                     (__attribute__((address_space(3))) void*)l, 16, 0, 0);
}

struct CellA {
    const u16 *Ah, *Al; long lda; long Kx;      // input activations (hi/lo bf16)
    const u16 *Wih_h, *Wih_l;                   // [2048, Kx]
    const u16 *Hh, *Hl;                         // recurrent h (hi/lo), [B,512]
    const u16 *Whh_h, *Whh_l;                   // [2048, 512]
    const float *bih, *bhh;
    float *c;                                   // cell state fp32 [B,512]
    u16 *oh, *ol;                               // h output hi/lo
};

// gates = A@Wih^T + H@Whh^T via double-bf16 split (3 products per staged chunk).
// Block tile: 64 rows x 16 j (x4 gates). 2-phase pipelined, dbuf 64KB LDS,
// XOR-swizzled tiles (pre-swizzled global source + swizzled ds_read).
extern "C" __global__ void __launch_bounds__(256, 2)
cell_kernel(CellA a0, CellA a1, int nblk)
{
    __shared__ char lds[65536];     // 2 bufs x {Ah 8K | Al 8K | Wh 8K | Wl 8K}

    // bijective XCD-chunked remap: XCD k owns contiguous logical range
    const int id  = blockIdx.x;
    const int id2 = (id & 7) * (nblk >> 3) + (id >> 3);
    const CellA& A = (id2 < 512) ? a0 : a1;
    const int rem  = id2 & 511;
    const int row0 = (rem & 15) * 64;
    const int j0   = (rem >> 4) * 16;

    const int tid  = threadIdx.x;
    const int wid  = tid >> 6;
    const int lane = tid & 63;
    const int l16  = lane & 15, lq = lane >> 4;
    const int arow = wid * 16 + l16;
    const int swzA = (l16 & 7) << 4;              // arow&7 == wrow&7 == l16&7

    // ---- staging per-thread geometry ----
    const int r0   = tid >> 3;                             // 64-wide rows (p0)
    const int kb64 = (((tid & 7) << 4) ^ ((r0 & 7) << 4)); // logical byte in 128B row
    const int r32  = tid >> 2;                             // 32-wide rows
    const int kb32 = (((tid & 3) << 4) ^ (((r32 & 7) << 4) & 48));

    auto grow = [&](int r) { return (r >> 4) * H_ + j0 + (r & 15); };

    // recurrent segment offsets (elements)
    const long recA0 = (long)(row0 + r0) * H_ + (kb64 >> 1);
    const long recA1 = recA0 + 32 * H_;
    const long recW0 = (long)grow(r0) * H_ + (kb64 >> 1);
    const long recW1 = (long)grow(r0 + 32) * H_ + (kb64 >> 1);

    // input segment offsets
    const long ldx = A.lda, Kx = A.Kx;
    const bool smallk = (Kx == 32);
    long inA0, inA1 = 0, inW0, inW1 = 0;
    if (smallk) {
        inA0 = (long)(row0 + r32) * ldx + (kb32 >> 1);
        inW0 = (long)grow(r32) * 32 + (kb32 >> 1);
    } else {
        inA0 = (long)(row0 + r0) * ldx + (kb64 >> 1);
        inA1 = inA0 + 32 * ldx;
        inW0 = (long)grow(r0) * Kx + (kb64 >> 1);
        inW1 = (long)grow(r0 + 32) * Kx + (kb64 >> 1);
    }

    const int ncIn = smallk ? 1 : (int)(Kx >> 6);
    const int NC   = ncIn + (H_ >> 6);

    auto stage64 = [&](char* lb, const u16* Ah, const u16* Al,
                       const u16* Wh, const u16* Wl,
                       long a0_, long a1_, long w0_, long w1_, int k0) {
        gl16(Ah + a0_ + k0, lb + tid * 16);
        gl16(Ah + a1_ + k0, lb + 4096  + tid * 16);
        gl16(Al + a0_ + k0, lb + 8192  + tid * 16);
        gl16(Al + a1_ + k0, lb + 12288 + tid * 16);
        gl16(Wh + w0_ + k0, lb + 16384 + tid * 16);
        gl16(Wh + w1_ + k0, lb + 20480 + tid * 16);
        gl16(Wl + w0_ + k0, lb + 24576 + tid * 16);
        gl16(Wl + w1_ + k0, lb + 28672 + tid * 16);
    };

    auto stageChunk = [&](int ci) {
        char* lb = lds + ((ci & 1) << 15);
        if (ci < ncIn) {
            if (smallk) {
                gl16(A.Ah + inA0,    lb + tid * 16);
                gl16(A.Al + inA0,    lb + 8192  + tid * 16);
                gl16(A.Wih_h + inW0, lb + 16384 + tid * 16);
                gl16(A.Wih_l + inW0, lb + 24576 + tid * 16);
            } else {
                stage64(lb, A.Ah, A.Al, A.Wih_h, A.Wih_l,
                        inA0, inA1, inW0, inW1, ci << 6);
            }
        } else {
            stage64(lb, A.Hh, A.Hl, A.Whh_h, A.Whh_l,
                    recA0, recA1, recW0, recW1, (ci - ncIn) << 6);
        }
    };

    f32x4 acc[4];
    #pragma unroll
    for (int g = 0; g < 4; ++g)
        #pragma unroll
        for (int q = 0; q < 4; ++q) acc[g][q] = 0.f;

    stageChunk(0);
    for (int i = 0; i < NC; ++i) {
        __syncthreads();                          // vmcnt(0): chunk i landed
        if (i + 1 < NC) stageChunk(i + 1);        // prefetch next (other buf)
        char* lb = lds + ((i & 1) << 15);
        if (smallk && i == 0) {
            const int kb = (lq * 16) ^ (swzA & 48);
            bf16x8 ah = *(const bf16x8*)(lb + arow * 64 + kb);
            bf16x8 al = *(const bf16x8*)(lb + 8192 + arow * 64 + kb);
            #pragma unroll
            for (int g = 0; g < 4; ++g) {
                const int wrow = g * 16 + l16;
                bf16x8 wh = *(const bf16x8*)(lb + 16384 + wrow * 64 + kb);
                bf16x8 wl = *(const bf16x8*)(lb + 24576 + wrow * 64 + kb);
                acc[g] = __builtin_amdgcn_mfma_f32_16x16x32_bf16(ah, wh, acc[g], 0, 0, 0);
                acc[g] = __builtin_amdgcn_mfma_f32_16x16x32_bf16(ah, wl, acc[g], 0, 0, 0);
                acc[g] = __builtin_amdgcn_mfma_f32_16x16x32_bf16(al, wh, acc[g], 0, 0, 0);
            }
        } else {
            #pragma unroll
            for (int ks = 0; ks < 2; ++ks) {
                const int kb = ((ks * 64) + lq * 16) ^ swzA;
                bf16x8 ah = *(const bf16x8*)(lb + arow * 128 + kb);
                bf16x8 al = *(const bf16x8*)(lb + 8192 + arow * 128 + kb);
                #pragma unroll
                for (int g = 0; g < 4; ++g) {
                    const int wrow = g * 16 + l16;
                    bf16x8 wh = *(const bf16x8*)(lb + 16384 + wrow * 128 + kb);
                    bf16x8 wl = *(const bf16x8*)(lb + 24576 + wrow * 128 + kb);
                    acc[g] = __builtin_amdgcn_mfma_f32_16x16x32_bf16(ah, wh, acc[g], 0, 0, 0);
                    acc[g] = __builtin_amdgcn_mfma_f32_16x16x32_bf16(ah, wl, acc[g], 0, 0, 0);
                    acc[g] = __builtin_amdgcn_mfma_f32_16x16x32_bf16(al, wh, acc[g], 0, 0, 0);
                }
            }
        }
    }

    // epilogue: C/D layout col=lane&15, row=(lane>>4)*4+reg -> 4 gates in-lane
    const int jj = j0 + l16;
    const float bi = A.bih[jj]          + A.bhh[jj];
    const float bf = A.bih[H_ + jj]     + A.bhh[H_ + jj];
    const float bg = A.bih[2 * H_ + jj] + A.bhh[2 * H_ + jj];
    const float bo = A.bih[3 * H_ + jj] + A.bhh[3 * H_ + jj];
    #pragma unroll
    for (int r = 0; r < 4; ++r) {
        const int  b    = row0 + wid * 16 + lq * 4 + r;
        const long base = (long)b * H_ + jj;
        const float cold = A.c[base];
        const float pi = acc[0][r] + bi, pf = acc[1][r] + bf;
        const float pg = acc[2][r] + bg, po = acc[3][r] + bo;
        const float cn = sig_(pf) * cold + sig_(pi) * tanhf(pg);
        const float hn = sig_(po) * tanhf(cn);
        A.c[base] = cn;
        const u16 hh = f2bf(hn);
        A.oh[base] = hh;
        A.ol[base] = f2bf(hn - bf2f(hh));
    }
}

// fp32 -> bf16 hi/lo split, 4 elements per thread
extern "C" __global__ void __launch_bounds__(256)
split4(const float* __restrict__ in, u16* __restrict__ hi, u16* __restrict__ lo, int n4)
{
    int i = blockIdx.x * 256 + threadIdx.x;
    if (i < n4) {
        float4 v = ((const float4*)in)[i];
        u16 h0 = f2bf(v.x), h1 = f2bf(v.y), h2 = f2bf(v.z), h3 = f2bf(v.w);
        ushort4 Hv; Hv.x = h0; Hv.y = h1; Hv.z = h2; Hv.w = h3;
        ushort4 Lv;
        Lv.x = f2bf(v.x - bf2f(h0)); Lv.y = f2bf(v.y - bf2f(h1));
        Lv.z = f2bf(v.z - bf2f(h2)); Lv.w = f2bf(v.w - bf2f(h3));
        ((ushort4*)hi)[i] = Hv; ((ushort4*)lo)[i] = Lv;
    }
}

extern "C" __global__ void __launch_bounds__(256)
zero16(uint4* p, int n)
{
    for (int i = blockIdx.x * 256 + threadIdx.x; i < n; i += gridDim.x * 256)
        p[i] = make_uint4(0, 0, 0, 0);
}

// mu / sigma heads for decoder step t ; h reconstructed as hi+lo
extern "C" __global__ void __launch_bounds__(256)
head_kernel(const u16* __restrict__ hh, const u16* __restrict__ hl,
            const float* __restrict__ W1, const float* __restrict__ b1,
            const float* __restrict__ W2, const float* __restrict__ b2,
            float* __restrict__ out, int t)
{
    int idx = blockIdx.x * 256 + threadIdx.x;          // 0..16383
    int b = idx >> 4, r = idx & 15, k = r & 7, which = r >> 3;
    const float* w  = (which ? W2 : W1) + (long)k * H_;
    const u16*   ph = hh + (long)b * H_;
    const u16*   pl = hl + (long)b * H_;
    float sum = 0.f;
    for (int d = 0; d < H_; d += 8) {
        uint4 uh = *(const uint4*)&ph[d];
        uint4 ul = *(const uint4*)&pl[d];
        float4 w0 = *(const float4*)&w[d];
        float4 w1 = *(const float4*)&w[d + 4];
        sum = fmaf(bf2f((u16)(uh.x & 0xffff)) + bf2f((u16)(ul.x & 0xffff)), w0.x, sum);
        sum = fmaf(bf2f((u16)(uh.x >> 16))    + bf2f((u16)(ul.x >> 16)),    w0.y, sum);
        sum = fmaf(bf2f((u16)(uh.y & 0xffff)) + bf2f((u16)(ul.y & 0xffff)), w0.z, sum);
        sum = fmaf(bf2f((u16)(uh.y >> 16))    + bf2f((u16)(ul.y >> 16)),    w0.w, sum);
        sum = fmaf(bf2f((u16)(uh.z & 0xffff)) + bf2f((u16)(ul.z & 0xffff)), w1.x, sum);
        sum = fmaf(bf2f((u16)(uh.z >> 16))    + bf2f((u16)(ul.z >> 16)),    w1.y, sum);
        sum = fmaf(bf2f((u16)(uh.w & 0xffff)) + bf2f((u16)(ul.w & 0xffff)), w1.z, sum);
        sum = fmaf(bf2f((u16)(uh.w >> 16))    + bf2f((u16)(ul.w >> 16)),    w1.w, sum);
    }
    long o = ((long)b * TAU_ + t) * K_ + k;
    if (which == 0) {
        out[o] = sum + b1[k];
    } else {
        float z  = 2.0f * (sum + b2[k]);
        float sp = fmaxf(z, 0.0f) + log1pf(expf(-fabsf(z)));
        out[(long)B_ * TAU_ * K_ + o] = 0.5f * sp;
    }
}

extern "C" void kernel_launch(void* const* d_in, const int* in_sizes, int n_in,
                              void* d_out, int out_size, void* d_ws, size_t ws_size,
                              hipStream_t stream)
{
    (void)in_sizes; (void)n_in; (void)out_size; (void)ws_size;

    const float* x     = (const float*)d_in[0];
    const float* eWih0 = (const float*)d_in[1];
    const float* eWhh0 = (const float*)d_in[2];
    const float* ebih0 = (const float*)d_in[3];
    const float* ebhh0 = (const float*)d_in[4];
    const float* eWih1 = (const float*)d_in[5];
    const float* eWhh1 = (const float*)d_in[6];
    const float* ebih1 = (const float*)d_in[7];
    const float* ebhh1 = (const float*)d_in[8];
    const float* dWih0 = (const float*)d_in[9];
    const float* dWhh0 = (const float*)d_in[10];
    const float* dbih0 = (const float*)d_in[11];
    const float* dbhh0 = (const float*)d_in[12];
    const float* dWih1 = (const float*)d_in[13];
    const float* dWhh1 = (const float*)d_in[14];
    const float* dbih1 = (const float*)d_in[15];
    const float* dbhh1 = (const float*)d_in[16];
    const float* W1    = (const float*)d_in[17];
    const float* b1    = (const float*)d_in[18];
    const float* W2    = (const float*)d_in[19];
    const float* b2    = (const float*)d_in[20];
    float* out = (float*)d_out;

    char* wsp = (char*)d_ws;
    auto take = [&](size_t n) { void* p = (void*)wsp; wsp += n; return p; };

    const size_t NX = (size_t)B_ * T_ * D_;
    u16* xh = (u16*)take(NX * 2);
    u16* xl = (u16*)take(NX * 2);

    const float* wsrc[8] = { eWih0, eWhh0, eWih1, eWhh1, dWih0, dWhh0, dWih1, dWhh1 };
    const size_t wn[8]   = { (size_t)2048 * 32, (size_t)2048 * 512, (size_t)2048 * 512,
                             (size_t)2048 * 512, (size_t)2048 * 512, (size_t)2048 * 512,
                             (size_t)2048 * 512, (size_t)2048 * 512 };
    u16 *wh[8], *wl[8];
    for (int i = 0; i < 8; ++i) { wh[i] = (u16*)take(wn[i] * 2); wl[i] = (u16*)take(wn[i] * 2); }

    const size_t NH = (size_t)B_ * H_;
    char* state0 = wsp;
    u16 *h0h[2], *h0l[2], *h1h[2], *h1l[2];
    for (int p = 0; p < 2; ++p) { h0h[p] = (u16*)take(NH * 2); h0l[p] = (u16*)take(NH * 2); }
    for (int p = 0; p < 2; ++p) { h1h[p] = (u16*)take(NH * 2); h1l[p] = (u16*)take(NH * 2); }
    float* c0 = (float*)take(NH * 4);
    float* c1 = (float*)take(NH * 4);
    const size_t stateBytes = (size_t)(wsp - state0);

    const dim3 blk(256);

    split4<<<dim3((unsigned)((NX / 4 + 255) / 256)), blk, 0, stream>>>(x, xh, xl, (int)(NX / 4));
    for (int i = 0; i < 8; ++i)
        split4<<<dim3((unsigned)((wn[i] / 4 + 255) / 256)), blk, 0, stream>>>(wsrc[i], wh[i], wl[i], (int)(wn[i] / 4));
    zero16<<<dim3(1024), blk, 0, stream>>>((uint4*)state0, (int)(stateBytes / 16));

    auto mkL0e = [&](int t, int pin, int pout) {
        CellA c;
        c.Ah = xh + (size_t)t * D_; c.Al = xl + (size_t)t * D_; c.lda = T_ * D_; c.Kx = D_;
        c.Wih_h = wh[0]; c.Wih_l = wl[0];
        c.Hh = h0h[pin]; c.Hl = h0l[pin];
        c.Whh_h = wh[1]; c.Whh_l = wl[1];
        c.bih = ebih0; c.bhh = ebhh0; c.c = c0;
        c.oh = h0h[pout]; c.ol = h0l[pout];
        return c;
    };
    auto mkL1e = [&](int pa, int pin, int pout) {
        CellA c;
        c.Ah = h0h[pa]; c.Al = h0l[pa]; c.lda = H_; c.Kx = H_;
        c.Wih_h = wh[2]; c.Wih_l = wl[2];
        c.Hh = h1h[pin]; c.Hl = h1l[pin];
        c.Whh_h = wh[3]; c.Whh_l = wl[3];
        c.bih = ebih1; c.bhh = ebhh1; c.c = c1;
        c.oh = h1h[pout]; c.ol = h1l[pout];
        return c;
    };
    auto mkL0d = [&](int pa, int pin, int pout) {
        CellA c;
        c.Ah = h1h[pa]; c.Al = h1l[pa]; c.lda = H_; c.Kx = H_;
        c.Wih_h = wh[4]; c.Wih_l = wl[4];
        c.Hh = h0h[pin]; c.Hl = h0l[pin];
        c.Whh_h = wh[5]; c.Whh_l = wl[5];
        c.bih = dbih0; c.bhh = dbhh0; c.c = c0;
        c.oh = h0h[pout]; c.ol = h0l[pout];
        return c;
    };
    auto mkL1d = [&](int pa, int pin, int pout) {
        CellA c;
        c.Ah = h0h[pa]; c.Al = h0l[pa]; c.lda = H_; c.Kx = H_;
        c.Wih_h = wh[6]; c.Wih_l = wl[6];
        c.Hh = h1h[pin]; c.Hl = h1l[pin];
        c.Whh_h = wh[7]; c.Whh_l = wl[7];
        c.bih = dbih1; c.bhh = dbhh1; c.c = c1;
        c.oh = h1h[pout]; c.ol = h1l[pout];
        return c;
    };

    int p0 = 1, p1 = 1;     // zeros live in buffer 1

    { CellA a = mkL0e(0, p0, p0 ^ 1);
      cell_kernel<<<dim3(512), blk, 0, stream>>>(a, a, 512); p0 ^= 1; }

    for (int t = 0; t < T_ - 1; ++t) {               // stagger: L1(t) || L0(t+1)
        CellA l1 = mkL1e(p0, p1, p1 ^ 1);
        CellA l0 = mkL0e(t + 1, p0, p0 ^ 1);
        cell_kernel<<<dim3(1024), blk, 0, stream>>>(l1, l0, 1024);
        p0 ^= 1; p1 ^= 1;
    }
    { CellA a = mkL1e(p0, p1, p1 ^ 1);
      cell_kernel<<<dim3(512), blk, 0, stream>>>(a, a, 512); p1 ^= 1; }

    for (int t = 0; t < TAU_; ++t) {
        CellA a = mkL0d(p1, p0, p0 ^ 1);
        cell_kernel<<<dim3(512), blk, 0, stream>>>(a, a, 512); p0 ^= 1;
        CellA b_ = mkL1d(p0, p1, p1 ^ 1);
        cell_kernel<<<dim3(512), blk, 0, stream>>>(b_, b_, 512); p1 ^= 1;
        head_kernel<<<dim3(64), blk, 0, stream>>>(h1h[p1], h1l[p1], W1, b1, W2, b2, out, t);
    }
}